// Round 1
// baseline (5465.962 us; speedup 1.0000x reference)
//
#include <hip/hip_runtime.h>
#include <hip/hip_bf16.h>

#define HYPER_DIM 128
#define LEAKY 0.2f
#define LN_EPS 1e-5f

// Scatter SpMM: out[dst[e]] += vals[e] * x[src[e]]  (rows of 128 floats)
// 32 threads (half-wave) per edge, each thread handles one float4 chunk.
__global__ __launch_bounds__(256) void spmm_scatter(
    const float* __restrict__ x, const float* __restrict__ vals,
    const int* __restrict__ src, const int* __restrict__ dst,
    float* __restrict__ out, int nnz) {
    int t = blockIdx.x * blockDim.x + threadIdx.x;
    int edge = t >> 5;
    int chunk = t & 31;            // 32 chunks of float4 = 128 floats
    if (edge >= nnz) return;
    float v = vals[edge];
    int s = src[edge];
    int d = dst[edge];
    float4 f = ((const float4*)(x + (size_t)s * HYPER_DIM))[chunk];
    float* o = out + (size_t)d * HYPER_DIM + chunk * 4;
    atomicAdd(o + 0, v * f.x);
    atomicAdd(o + 1, v * f.y);
    atomicAdd(o + 2, v * f.z);
    atomicAdd(o + 3, v * f.w);
}

// Fused (optional leaky-ReLU) + LayerNorm + residual. One wave per row.
__global__ __launch_bounds__(256) void ln_residual(
    const float* __restrict__ h, const float* __restrict__ res,
    const float* __restrict__ gamma, const float* __restrict__ beta,
    float* __restrict__ out, int n_rows, int apply_leaky) {
    int wave_in_block = threadIdx.x >> 6;
    int lane = threadIdx.x & 63;
    int row = blockIdx.x * (blockDim.x >> 6) + wave_in_block;
    if (row >= n_rows) return;

    float2 xv = ((const float2*)(h + (size_t)row * HYPER_DIM))[lane];
    if (apply_leaky) {
        xv.x = xv.x >= 0.f ? xv.x : LEAKY * xv.x;
        xv.y = xv.y >= 0.f ? xv.y : LEAKY * xv.y;
    }
    // mean
    float s = xv.x + xv.y;
    #pragma unroll
    for (int o = 32; o > 0; o >>= 1) s += __shfl_xor(s, o);
    float mu = s * (1.f / HYPER_DIM);
    float dx = xv.x - mu, dy = xv.y - mu;
    float vs = dx * dx + dy * dy;
    #pragma unroll
    for (int o = 32; o > 0; o >>= 1) vs += __shfl_xor(vs, o);
    float inv = rsqrtf(vs * (1.f / HYPER_DIM) + LN_EPS);

    float2 g = ((const float2*)gamma)[lane];
    float2 b = ((const float2*)beta)[lane];
    float2 r = ((const float2*)(res + (size_t)row * HYPER_DIM))[lane];
    float2 o2;
    o2.x = dx * inv * g.x + b.x + r.x;
    o2.y = dy * inv * g.y + b.y + r.y;
    ((float2*)(out + (size_t)row * HYPER_DIM))[lane] = o2;
}

extern "C" void kernel_launch(void* const* d_in, const int* in_sizes, int n_in,
                              void* d_out, int out_size, void* d_ws, size_t ws_size,
                              hipStream_t stream) {
    const float* ego   = (const float*)d_in[0];   // (N, 128)
    const float* vals  = (const float*)d_in[1];   // (NNZ,)
    const float* gamma = (const float*)d_in[2];   // (2, 128)
    const float* beta  = (const float*)d_in[3];   // (2, 128)
    const int*   rows  = (const int*)d_in[4];     // (NNZ,)
    const int*   cols  = (const int*)d_in[5];     // (NNZ,)
    // d_in[6] = n_users (unused: output concat == full embs)

    const int N   = in_sizes[0] / HYPER_DIM;      // 50000
    const int NNZ = in_sizes[1];                  // 800000
    const size_t row_bytes = (size_t)N * HYPER_DIM * sizeof(float);

    float* out  = (float*)d_out;
    float* bufA = (float*)d_ws;                   // 25.6 MB
    float* bufB = bufA + (size_t)N * HYPER_DIM;   // 25.6 MB

    const int spmm_threads = 256;
    const int spmm_blocks  = (NNZ * 32 + spmm_threads - 1) / spmm_threads;
    const int ln_threads = 256;
    const int ln_blocks  = (N + 3) / 4;           // 4 waves/block, 1 row/wave

    // ---- layer 0 ----
    // ht = scatter: out[cols[e]] += vals[e] * ego[rows[e]]
    hipMemsetAsync(bufA, 0, row_bytes, stream);
    spmm_scatter<<<spmm_blocks, spmm_threads, 0, stream>>>(ego, vals, rows, cols, bufA, NNZ);
    // h = scatter: out[rows[e]] += vals[e] * ht[cols[e]]
    hipMemsetAsync(bufB, 0, row_bytes, stream);
    spmm_scatter<<<spmm_blocks, spmm_threads, 0, stream>>>(bufA, vals, cols, rows, bufB, NNZ);
    // embs1 = LN(leaky(h)) + ego   (in-place on bufB)
    ln_residual<<<ln_blocks, ln_threads, 0, stream>>>(bufB, ego, gamma, beta, bufB, N, 1);

    // ---- layer 1 ----
    hipMemsetAsync(bufA, 0, row_bytes, stream);
    spmm_scatter<<<spmm_blocks, spmm_threads, 0, stream>>>(bufB, vals, rows, cols, bufA, NNZ);
    hipMemsetAsync(out, 0, row_bytes, stream);
    spmm_scatter<<<spmm_blocks, spmm_threads, 0, stream>>>(bufA, vals, cols, rows, out, NNZ);
    ln_residual<<<ln_blocks, ln_threads, 0, stream>>>(out, ego, gamma + HYPER_DIM, beta + HYPER_DIM, out, N, 0);
}

// Round 2
// 582.395 us; speedup vs baseline: 9.3853x; 9.3853x over previous
//
#include <hip/hip_runtime.h>
#include <hip/hip_bf16.h>

#define HYPER_DIM 128
#define LEAKY 0.2f
#define LN_EPS 1e-5f

// ---------- CSR build ----------

// Histogram both key arrays in one pass.
__global__ __launch_bounds__(256) void histo2(
    const int* __restrict__ rows, const int* __restrict__ cols,
    int* __restrict__ cnt_r, int* __restrict__ cnt_c, int nnz) {
    int e = blockIdx.x * blockDim.x + threadIdx.x;
    if (e >= nnz) return;
    atomicAdd(&cnt_r[rows[e]], 1);
    atomicAdd(&cnt_c[cols[e]], 1);
}

// Exclusive scan of two count arrays (block 0 -> array 0, block 1 -> array 1).
// Wave-shuffle scan within waves, thread-0 serial scan of 16 wave sums.
__global__ __launch_bounds__(1024) void scan2(
    const int* __restrict__ c0, int* __restrict__ r0,
    const int* __restrict__ c1, int* __restrict__ r1, int n) {
    const int* cnt = blockIdx.x ? c1 : c0;
    int* rp = blockIdx.x ? r1 : r0;
    __shared__ int wsum[16];
    __shared__ int s_off[16];
    __shared__ int s_carry;
    int lane = threadIdx.x & 63;
    int wid = threadIdx.x >> 6;
    if (threadIdx.x == 0) s_carry = 0;
    __syncthreads();
    for (int base = 0; base < n; base += 1024) {
        int i = base + threadIdx.x;
        int v = (i < n) ? cnt[i] : 0;
        int incl = v;
        #pragma unroll
        for (int off = 1; off < 64; off <<= 1) {
            int t = __shfl_up(incl, off);
            if (lane >= off) incl += t;
        }
        if (lane == 63) wsum[wid] = incl;
        __syncthreads();
        if (threadIdx.x == 0) {
            int run = s_carry;
            #pragma unroll
            for (int w = 0; w < 16; ++w) { int t = wsum[w]; s_off[w] = run; run += t; }
            s_carry = run;
        }
        __syncthreads();
        if (i < n) rp[i] = s_off[wid] + incl - v;
        __syncthreads();
    }
    if (threadIdx.x == 0) rp[n] = s_carry;
}

// Scatter edges into CSR order: for each edge, reserve a slot in its key's
// segment, store the "other" endpoint and the value.
__global__ __launch_bounds__(256) void csr_fill(
    const int* __restrict__ key, const int* __restrict__ other,
    const float* __restrict__ vals, int* __restrict__ cursor,
    int* __restrict__ oth_out, float* __restrict__ val_out, int nnz) {
    int e = blockIdx.x * blockDim.x + threadIdx.x;
    if (e >= nnz) return;
    int p = atomicAdd(&cursor[key[e]], 1);
    oth_out[p] = other[e];
    val_out[p] = vals[e];
}

// ---------- gather SpMM ----------
// One wave per destination row; 64 lanes x float2 = the full 128-dim row.
__global__ __launch_bounds__(256) void spmm_gather(
    const float* __restrict__ x, const int* __restrict__ row_ptr,
    const int* __restrict__ src, const float* __restrict__ val,
    float* __restrict__ out, int n) {
    int wid = threadIdx.x >> 6;
    int lane = threadIdx.x & 63;
    int row = blockIdx.x * 4 + wid;
    if (row >= n) return;
    int beg = row_ptr[row];
    int end = row_ptr[row + 1];
    float ax = 0.f, ay = 0.f;
    int i = beg;
    for (; i + 1 < end; i += 2) {
        int s0 = src[i], s1 = src[i + 1];
        float v0 = val[i], v1 = val[i + 1];
        float2 x0 = ((const float2*)(x + (size_t)s0 * HYPER_DIM))[lane];
        float2 x1 = ((const float2*)(x + (size_t)s1 * HYPER_DIM))[lane];
        ax += v0 * x0.x + v1 * x1.x;
        ay += v0 * x0.y + v1 * x1.y;
    }
    if (i < end) {
        int s0 = src[i];
        float v0 = val[i];
        float2 x0 = ((const float2*)(x + (size_t)s0 * HYPER_DIM))[lane];
        ax += v0 * x0.x;
        ay += v0 * x0.y;
    }
    float2 o = {ax, ay};
    ((float2*)(out + (size_t)row * HYPER_DIM))[lane] = o;
}

// ---------- fused leaky-ReLU + LayerNorm + residual ----------
__global__ __launch_bounds__(256) void ln_residual(
    const float* __restrict__ h, const float* __restrict__ res,
    const float* __restrict__ gamma, const float* __restrict__ beta,
    float* __restrict__ out, int n_rows, int apply_leaky) {
    int wave_in_block = threadIdx.x >> 6;
    int lane = threadIdx.x & 63;
    int row = blockIdx.x * (blockDim.x >> 6) + wave_in_block;
    if (row >= n_rows) return;

    float2 xv = ((const float2*)(h + (size_t)row * HYPER_DIM))[lane];
    if (apply_leaky) {
        xv.x = xv.x >= 0.f ? xv.x : LEAKY * xv.x;
        xv.y = xv.y >= 0.f ? xv.y : LEAKY * xv.y;
    }
    float s = xv.x + xv.y;
    #pragma unroll
    for (int o = 32; o > 0; o >>= 1) s += __shfl_xor(s, o);
    float mu = s * (1.f / HYPER_DIM);
    float dx = xv.x - mu, dy = xv.y - mu;
    float vs = dx * dx + dy * dy;
    #pragma unroll
    for (int o = 32; o > 0; o >>= 1) vs += __shfl_xor(vs, o);
    float inv = rsqrtf(vs * (1.f / HYPER_DIM) + LN_EPS);

    float2 g = ((const float2*)gamma)[lane];
    float2 b = ((const float2*)beta)[lane];
    float2 r = ((const float2*)(res + (size_t)row * HYPER_DIM))[lane];
    float2 o2;
    o2.x = dx * inv * g.x + b.x + r.x;
    o2.y = dy * inv * g.y + b.y + r.y;
    ((float2*)(out + (size_t)row * HYPER_DIM))[lane] = o2;
}

extern "C" void kernel_launch(void* const* d_in, const int* in_sizes, int n_in,
                              void* d_out, int out_size, void* d_ws, size_t ws_size,
                              hipStream_t stream) {
    const float* ego   = (const float*)d_in[0];   // (N, 128)
    const float* vals  = (const float*)d_in[1];   // (NNZ,)
    const float* gamma = (const float*)d_in[2];   // (2, 128)
    const float* beta  = (const float*)d_in[3];   // (2, 128)
    const int*   rows  = (const int*)d_in[4];     // (NNZ,)
    const int*   cols  = (const int*)d_in[5];     // (NNZ,)

    const int N   = in_sizes[0] / HYPER_DIM;      // 50000
    const int NNZ = in_sizes[1];                  // 800000
    const int RP  = (N + 8) & ~7;                 // padded row_ptr size (>= N+1)

    float* out = (float*)d_out;
    char* w = (char*)d_ws;
    float* bufA  = (float*)w; w += (size_t)N * HYPER_DIM * 4;
    float* bufB  = (float*)w; w += (size_t)N * HYPER_DIM * 4;
    int*   rp_r  = (int*)w;   w += (size_t)RP * 4;
    int*   rp_c  = (int*)w;   w += (size_t)RP * 4;
    int*   cur_r = (int*)w;   w += (size_t)N * 4;   // cur_r, cur_c contiguous
    int*   cur_c = (int*)w;   w += (size_t)N * 4;
    int*   oth_r = (int*)w;   w += (size_t)NNZ * 4;
    float* val_r = (float*)w; w += (size_t)NNZ * 4;
    int*   oth_c = (int*)w;   w += (size_t)NNZ * 4;
    float* val_c = (float*)w; w += (size_t)NNZ * 4;

    const int eblocks = (NNZ + 255) / 256;

    // ---- build both CSRs (keyed by rows, and by cols) ----
    hipMemsetAsync(cur_r, 0, (size_t)2 * N * 4, stream);
    histo2<<<eblocks, 256, 0, stream>>>(rows, cols, cur_r, cur_c, NNZ);
    scan2<<<2, 1024, 0, stream>>>(cur_r, rp_r, cur_c, rp_c, N);
    hipMemcpyAsync(cur_r, rp_r, (size_t)N * 4, hipMemcpyDeviceToDevice, stream);
    hipMemcpyAsync(cur_c, rp_c, (size_t)N * 4, hipMemcpyDeviceToDevice, stream);
    csr_fill<<<eblocks, 256, 0, stream>>>(rows, cols, vals, cur_r, oth_r, val_r, NNZ);
    csr_fill<<<eblocks, 256, 0, stream>>>(cols, rows, vals, cur_c, oth_c, val_c, NNZ);

    const int sblocks  = (N + 3) / 4;   // 4 waves/block, 1 row/wave
    const int ln_blocks = (N + 3) / 4;

    // ---- layer 0 ----
    // ht[c] = sum_{e: cols[e]==c} vals[e] * ego[rows[e]]   (CSR keyed by cols)
    spmm_gather<<<sblocks, 256, 0, stream>>>(ego, rp_c, oth_c, val_c, bufA, N);
    // h[r] = sum_{e: rows[e]==r} vals[e] * ht[cols[e]]     (CSR keyed by rows)
    spmm_gather<<<sblocks, 256, 0, stream>>>(bufA, rp_r, oth_r, val_r, bufB, N);
    ln_residual<<<ln_blocks, 256, 0, stream>>>(bufB, ego, gamma, beta, bufB, N, 1);

    // ---- layer 1 ----
    spmm_gather<<<sblocks, 256, 0, stream>>>(bufB, rp_c, oth_c, val_c, bufA, N);
    spmm_gather<<<sblocks, 256, 0, stream>>>(bufA, rp_r, oth_r, val_r, out, N);
    ln_residual<<<ln_blocks, 256, 0, stream>>>(out, ego, gamma + HYPER_DIM, beta + HYPER_DIM, out, N, 0);
}

// Round 3
// 494.836 us; speedup vs baseline: 11.0460x; 1.1769x over previous
//
#include <hip/hip_runtime.h>
#include <hip/hip_bf16.h>

#define HD 128
#define R 8            // counter/cursor replicas (contention reduction)
#define LEAKY 0.2f
#define LN_EPS 1e-5f
#define TILE 4096      // scan tile: 256 threads x 16 items

// ---------- CSR build ----------

// Replicated histogram of both key arrays in one pass.
__global__ __launch_bounds__(256) void histo2(
    const int* __restrict__ rows, const int* __restrict__ cols,
    int* __restrict__ cnt_r, int* __restrict__ cnt_c, int nnz, int n) {
    int e = blockIdx.x * 256 + threadIdx.x;
    if (e >= nnz) return;
    int r = blockIdx.x & (R - 1);
    atomicAdd(&cnt_r[r * n + rows[e]], 1);
    atomicAdd(&cnt_c[r * n + cols[e]], 1);
}

// Device-wide exclusive scan over the 2 count arrays, in (bin-major,
// replica-minor) logical order p = b*R + r, reading cnt[r*n + b].
// k1: per-tile sums.
__global__ __launch_bounds__(256) void scan_sum(
    const int* __restrict__ cnt, int* __restrict__ partials, int n, int tiles) {
    int a = blockIdx.y;
    const int* base = cnt + (size_t)a * n * R;
    int M = n * R;
    int t0 = blockIdx.x * TILE + threadIdx.x * 16;
    int s = 0;
    #pragma unroll
    for (int j = 0; j < 16; ++j) {
        int p = t0 + j;
        if (p < M) s += base[(p & (R - 1)) * n + (p >> 3)];
    }
    #pragma unroll
    for (int off = 32; off; off >>= 1) s += __shfl_xor(s, off);
    __shared__ int ws[4];
    int lane = threadIdx.x & 63, wid = threadIdx.x >> 6;
    if (lane == 0) ws[wid] = s;
    __syncthreads();
    if (threadIdx.x == 0)
        partials[a * tiles + blockIdx.x] = ws[0] + ws[1] + ws[2] + ws[3];
}

// k2: serial exclusive scan of tile partials (2 arrays, ~98 each) + rp[N].
__global__ void scan_partials(int* __restrict__ partials, int tiles,
                              int* __restrict__ rp_r, int* __restrict__ rp_c,
                              int n, int nnz) {
    int a = threadIdx.x;
    if (a < 2) {
        int* p = partials + a * tiles;
        int run = 0;
        for (int i = 0; i < tiles; ++i) { int v = p[i]; p[i] = run; run += v; }
        (a ? rp_c : rp_r)[n] = nnz;
    }
}

// k3: re-scan tiles, write cursor init in-place (cnt -> cursor) and rp[b]
// (the replica-0 offset of each bin).
__global__ __launch_bounds__(256) void scan_apply(
    int* __restrict__ cnt, const int* __restrict__ partials,
    int* __restrict__ rp_r, int* __restrict__ rp_c, int n, int tiles) {
    int a = blockIdx.y;
    int* base = cnt + (size_t)a * n * R;
    int* rp = a ? rp_c : rp_r;
    int M = n * R;
    int t0 = blockIdx.x * TILE + threadIdx.x * 16;
    int v[16];
    int s = 0;
    #pragma unroll
    for (int j = 0; j < 16; ++j) {
        int p = t0 + j;
        v[j] = (p < M) ? base[(p & (R - 1)) * n + (p >> 3)] : 0;
        s += v[j];
    }
    int lane = threadIdx.x & 63, wid = threadIdx.x >> 6;
    int incl = s;
    #pragma unroll
    for (int off = 1; off < 64; off <<= 1) {
        int t = __shfl_up(incl, off);
        if (lane >= off) incl += t;
    }
    __shared__ int wsum[4], woff[4];
    if (lane == 63) wsum[wid] = incl;
    __syncthreads();
    if (threadIdx.x == 0) {
        int run = 0;
        #pragma unroll
        for (int w = 0; w < 4; ++w) { woff[w] = run; run += wsum[w]; }
    }
    __syncthreads();
    int excl = partials[a * tiles + blockIdx.x] + woff[wid] + incl - s;
    #pragma unroll
    for (int j = 0; j < 16; ++j) {
        int p = t0 + j;
        if (p < M) {
            int b = p >> 3, r = p & (R - 1);
            base[r * n + b] = excl;
            if (r == 0) rp[b] = excl;
            excl += v[j];
        }
    }
}

// Fill BOTH CSRs in one pass with replicated cursors.
__global__ __launch_bounds__(256) void csr_fill2(
    const int* __restrict__ rows, const int* __restrict__ cols,
    const float* __restrict__ vals,
    int* __restrict__ cur_r, int* __restrict__ cur_c,
    int* __restrict__ oth_r, float* __restrict__ val_r,
    int* __restrict__ oth_c, float* __restrict__ val_c, int nnz, int n) {
    int e = blockIdx.x * 256 + threadIdx.x;
    if (e >= nnz) return;
    int r = blockIdx.x & (R - 1);
    int ro = rows[e], co = cols[e];
    float v = vals[e];
    int p1 = atomicAdd(&cur_r[r * n + ro], 1);
    oth_r[p1] = co; val_r[p1] = v;
    int p2 = atomicAdd(&cur_c[r * n + co], 1);
    oth_c[p2] = ro; val_c[p2] = v;
}

// ---------- gather SpMM (+ optional fused leaky/LN/residual) ----------
// One wave per output row; halves of the wave each process alternate edges
// with float4/lane (16 B/lane => one vmem instr gathers 2 rows = 1 KB).
// post: 0 = none, 1 = leaky+LN+residual, 2 = LN+residual.
__global__ __launch_bounds__(256) void spmm_f4(
    const float* __restrict__ x, const int* __restrict__ rp,
    const int* __restrict__ src, const float* __restrict__ val,
    const float* __restrict__ res, const float* __restrict__ gamma,
    const float* __restrict__ beta, float* __restrict__ out,
    int n, int post) {
    int wid = threadIdx.x >> 6, lane = threadIdx.x & 63;
    int row = blockIdx.x * 4 + wid;
    if (row >= n) return;
    int half = lane >> 5, q = lane & 31;
    int beg = rp[row], end = rp[row + 1];
    float4 acc = {0.f, 0.f, 0.f, 0.f};
    int i = beg + half;
    for (; i + 2 < end; i += 4) {
        int s0 = src[i], s1 = src[i + 2];
        float v0 = val[i], v1 = val[i + 2];
        float4 a0 = ((const float4*)(x + (size_t)s0 * HD))[q];
        float4 a1 = ((const float4*)(x + (size_t)s1 * HD))[q];
        acc.x += v0 * a0.x + v1 * a1.x;
        acc.y += v0 * a0.y + v1 * a1.y;
        acc.z += v0 * a0.z + v1 * a1.z;
        acc.w += v0 * a0.w + v1 * a1.w;
    }
    for (; i < end; i += 2) {
        int s0 = src[i];
        float v0 = val[i];
        float4 a0 = ((const float4*)(x + (size_t)s0 * HD))[q];
        acc.x += v0 * a0.x;
        acc.y += v0 * a0.y;
        acc.z += v0 * a0.z;
        acc.w += v0 * a0.w;
    }
    // combine the two halves (each lane then holds the full-row chunk sum)
    acc.x += __shfl_xor(acc.x, 32);
    acc.y += __shfl_xor(acc.y, 32);
    acc.z += __shfl_xor(acc.z, 32);
    acc.w += __shfl_xor(acc.w, 32);

    if (post) {
        if (post == 1) {
            acc.x = acc.x >= 0.f ? acc.x : LEAKY * acc.x;
            acc.y = acc.y >= 0.f ? acc.y : LEAKY * acc.y;
            acc.z = acc.z >= 0.f ? acc.z : LEAKY * acc.z;
            acc.w = acc.w >= 0.f ? acc.w : LEAKY * acc.w;
        }
        float t = acc.x + acc.y + acc.z + acc.w;
        #pragma unroll
        for (int off = 16; off; off >>= 1) t += __shfl_xor(t, off);
        float mu = t * (1.f / HD);
        float dx = acc.x - mu, dy = acc.y - mu, dz = acc.z - mu, dw = acc.w - mu;
        float vs = dx * dx + dy * dy + dz * dz + dw * dw;
        #pragma unroll
        for (int off = 16; off; off >>= 1) vs += __shfl_xor(vs, off);
        float inv = rsqrtf(vs * (1.f / HD) + LN_EPS);
        float4 g = ((const float4*)gamma)[q];
        float4 b = ((const float4*)beta)[q];
        float4 rr = ((const float4*)(res + (size_t)row * HD))[q];
        acc.x = dx * inv * g.x + b.x + rr.x;
        acc.y = dy * inv * g.y + b.y + rr.y;
        acc.z = dz * inv * g.z + b.z + rr.z;
        acc.w = dw * inv * g.w + b.w + rr.w;
    }
    if (half == 0) ((float4*)(out + (size_t)row * HD))[q] = acc;
}

extern "C" void kernel_launch(void* const* d_in, const int* in_sizes, int n_in,
                              void* d_out, int out_size, void* d_ws, size_t ws_size,
                              hipStream_t stream) {
    const float* ego   = (const float*)d_in[0];
    const float* vals  = (const float*)d_in[1];
    const float* gamma = (const float*)d_in[2];
    const float* beta  = (const float*)d_in[3];
    const int*   rows  = (const int*)d_in[4];
    const int*   cols  = (const int*)d_in[5];

    const int N   = in_sizes[0] / HD;   // 50000
    const int NNZ = in_sizes[1];        // 800000

    float* out = (float*)d_out;
    char* w = (char*)d_ws;
    float* bufA  = (float*)w; w += (size_t)N * HD * 4;
    float* bufB  = (float*)w; w += (size_t)N * HD * 4;
    int*   rp_r  = (int*)w;   w += (size_t)(N + 4) * 4;
    int*   rp_c  = (int*)w;   w += (size_t)(N + 4) * 4;
    int*   oth_r = (int*)w;   w += (size_t)NNZ * 4;
    float* val_r = (float*)w; w += (size_t)NNZ * 4;
    int*   oth_c = (int*)w;   w += (size_t)NNZ * 4;
    float* val_c = (float*)w; w += (size_t)NNZ * 4;
    // scratch that is dead before the SpMMs touch bufA/bufB:
    int* cnt      = (int*)bufA;   // 2*R*N ints = 3.2 MB  (cnt_r | cnt_c)
    int* partials = (int*)bufB;   // 2*tiles ints

    int* cnt_r = cnt;
    int* cnt_c = cnt + (size_t)R * N;

    const int eblocks = (NNZ + 255) / 256;
    const int tiles = (N * R + TILE - 1) / TILE;

    // ---- build both CSRs ----
    hipMemsetAsync(cnt, 0, (size_t)2 * R * N * 4, stream);
    histo2<<<eblocks, 256, 0, stream>>>(rows, cols, cnt_r, cnt_c, NNZ, N);
    scan_sum<<<dim3(tiles, 2), 256, 0, stream>>>(cnt, partials, N, tiles);
    scan_partials<<<1, 64, 0, stream>>>(partials, tiles, rp_r, rp_c, N, NNZ);
    scan_apply<<<dim3(tiles, 2), 256, 0, stream>>>(cnt, partials, rp_r, rp_c, N, tiles);
    csr_fill2<<<eblocks, 256, 0, stream>>>(rows, cols, vals, cnt_r, cnt_c,
                                           oth_r, val_r, oth_c, val_c, NNZ, N);

    const int sblocks = (N + 3) / 4;

    // ---- layer 0 ----
    spmm_f4<<<sblocks, 256, 0, stream>>>(ego, rp_c, oth_c, val_c,
                                         nullptr, nullptr, nullptr, bufA, N, 0);
    spmm_f4<<<sblocks, 256, 0, stream>>>(bufA, rp_r, oth_r, val_r,
                                         ego, gamma, beta, bufB, N, 1);
    // ---- layer 1 ----
    spmm_f4<<<sblocks, 256, 0, stream>>>(bufB, rp_c, oth_c, val_c,
                                         nullptr, nullptr, nullptr, bufA, N, 0);
    spmm_f4<<<sblocks, 256, 0, stream>>>(bufA, rp_r, oth_r, val_r,
                                         ego, gamma + HD, beta + HD, out, N, 2);
}

// Round 4
// 427.473 us; speedup vs baseline: 12.7867x; 1.1576x over previous
//
#include <hip/hip_runtime.h>
#include <hip/hip_bf16.h>

#define HD 128
#define R 16           // counter/cursor replicas
#define LEAKY 0.2f
#define LN_EPS 1e-5f
#define TILE 4096      // scan tile: 256 threads x 16 items

// ---- bf16 helpers (manual, RNE) ----
__device__ __forceinline__ unsigned short bfr(float f) {
    unsigned int b = __float_as_uint(f);
    return (unsigned short)((b + 0x7fffu + ((b >> 16) & 1u)) >> 16);
}
__device__ __forceinline__ float blo(unsigned int u) { return __uint_as_float(u << 16); }
__device__ __forceinline__ float bhi(unsigned int u) { return __uint_as_float(u & 0xffff0000u); }

// ---------- fp32 -> bf16 conversion (ego) ----------
__global__ __launch_bounds__(256) void f32_to_bf16(
    const float* __restrict__ x, unsigned short* __restrict__ y, int n4) {
    int i = blockIdx.x * 256 + threadIdx.x;
    if (i >= n4) return;
    float4 f = ((const float4*)x)[i];
    ushort4 u;
    u.x = bfr(f.x); u.y = bfr(f.y); u.z = bfr(f.z); u.w = bfr(f.w);
    ((ushort4*)y)[i] = u;
}

// ---------- CSR build ----------
__global__ __launch_bounds__(256) void histo2(
    const int* __restrict__ rows, const int* __restrict__ cols,
    int* __restrict__ cnt_r, int* __restrict__ cnt_c, int nnz, int n) {
    int e = blockIdx.x * 256 + threadIdx.x;
    if (e >= nnz) return;
    int r = blockIdx.x & (R - 1);
    atomicAdd(&cnt_r[r * n + rows[e]], 1);
    atomicAdd(&cnt_c[r * n + cols[e]], 1);
}

// Exclusive scan over logical order p = bin*R + replica, reading cnt[r*n+b].
__global__ __launch_bounds__(256) void scan_sum(
    const int* __restrict__ cnt, int* __restrict__ partials, int n, int tiles) {
    int a = blockIdx.y;
    const int* base = cnt + (size_t)a * n * R;
    int M = n * R;
    int t0 = blockIdx.x * TILE + threadIdx.x * 16;
    int s = 0;
    #pragma unroll
    for (int j = 0; j < 16; ++j) {
        int p = t0 + j;
        if (p < M) s += base[(p & (R - 1)) * n + (p >> 4)];
    }
    #pragma unroll
    for (int off = 32; off; off >>= 1) s += __shfl_xor(s, off);
    __shared__ int ws[4];
    int lane = threadIdx.x & 63, wid = threadIdx.x >> 6;
    if (lane == 0) ws[wid] = s;
    __syncthreads();
    if (threadIdx.x == 0)
        partials[a * tiles + blockIdx.x] = ws[0] + ws[1] + ws[2] + ws[3];
}

// Wave-parallel exclusive scan of tile partials (tiles <= 256), 2 waves.
__global__ __launch_bounds__(128) void scan_partials(
    int* __restrict__ partials, int tiles,
    int* __restrict__ rp_r, int* __restrict__ rp_c, int n, int nnz) {
    int wid = threadIdx.x >> 6, lane = threadIdx.x & 63;
    int* p = partials + wid * tiles;
    int v[4], s = 0;
    #pragma unroll
    for (int j = 0; j < 4; ++j) {
        int idx = lane * 4 + j;
        v[j] = (idx < tiles) ? p[idx] : 0;
        s += v[j];
    }
    int incl = s;
    #pragma unroll
    for (int off = 1; off < 64; off <<= 1) {
        int t = __shfl_up(incl, off);
        if (lane >= off) incl += t;
    }
    int excl = incl - s;
    #pragma unroll
    for (int j = 0; j < 4; ++j) {
        int idx = lane * 4 + j;
        if (idx < tiles) p[idx] = excl;
        excl += v[j];
    }
    if (lane == 0) (wid ? rp_c : rp_r)[n] = nnz;
}

// Re-scan tiles, convert cnt -> cursor init in-place, emit rp[b] (replica-0 offset).
__global__ __launch_bounds__(256) void scan_apply(
    int* __restrict__ cnt, const int* __restrict__ partials,
    int* __restrict__ rp_r, int* __restrict__ rp_c, int n, int tiles) {
    int a = blockIdx.y;
    int* base = cnt + (size_t)a * n * R;
    int* rp = a ? rp_c : rp_r;
    int M = n * R;
    int t0 = blockIdx.x * TILE + threadIdx.x * 16;
    int v[16];
    int s = 0;
    #pragma unroll
    for (int j = 0; j < 16; ++j) {
        int p = t0 + j;
        v[j] = (p < M) ? base[(p & (R - 1)) * n + (p >> 4)] : 0;
        s += v[j];
    }
    int lane = threadIdx.x & 63, wid = threadIdx.x >> 6;
    int incl = s;
    #pragma unroll
    for (int off = 1; off < 64; off <<= 1) {
        int t = __shfl_up(incl, off);
        if (lane >= off) incl += t;
    }
    __shared__ int wsum[4], woff[4];
    if (lane == 63) wsum[wid] = incl;
    __syncthreads();
    if (threadIdx.x == 0) {
        int run = 0;
        #pragma unroll
        for (int w = 0; w < 4; ++w) { woff[w] = run; run += wsum[w]; }
    }
    __syncthreads();
    int excl = partials[a * tiles + blockIdx.x] + woff[wid] + incl - s;
    #pragma unroll
    for (int j = 0; j < 16; ++j) {
        int p = t0 + j;
        if (p < M) {
            int b = p >> 4, r = p & (R - 1);
            base[r * n + b] = excl;
            if (r == 0) rp[b] = excl;
            excl += v[j];
        }
    }
}

// Fill BOTH CSRs in one pass; interleaved (other, val_bits) int2 entries.
__global__ __launch_bounds__(256) void csr_fill2(
    const int* __restrict__ rows, const int* __restrict__ cols,
    const float* __restrict__ vals,
    int* __restrict__ cur_r, int* __restrict__ cur_c,
    int2* __restrict__ ent_r, int2* __restrict__ ent_c, int nnz, int n) {
    int e = blockIdx.x * 256 + threadIdx.x;
    if (e >= nnz) return;
    int r = blockIdx.x & (R - 1);
    int ro = rows[e], co = cols[e];
    int vb = __float_as_int(vals[e]);
    int p1 = atomicAdd(&cur_r[r * n + ro], 1);
    ent_r[p1] = make_int2(co, vb);
    int p2 = atomicAdd(&cur_c[r * n + co], 1);
    ent_c[p2] = make_int2(ro, vb);
}

// ---------- bf16-gather SpMM (+ optional fused leaky/LN/residual) ----------
// One wave per output row. Quarter-wave (16 lanes) x 16 B (8 bf16) covers a
// 256 B row; the 4 quarters process interleaved edges, combined at the end.
// post: 0 = none (bf16 out), 1 = leaky+LN+res (bf16 out), 2 = LN+res (fp32 out).
__global__ __launch_bounds__(256) void spmm_bf(
    const unsigned short* __restrict__ x, const int* __restrict__ rp,
    const int2* __restrict__ ent,
    const float* __restrict__ res, const float* __restrict__ gamma,
    const float* __restrict__ beta,
    unsigned short* __restrict__ out_bf, float* __restrict__ out_f32,
    int n, int post) {
    int wid = threadIdx.x >> 6, lane = threadIdx.x & 63;
    int row = blockIdx.x * 4 + wid;
    if (row >= n) return;
    int quarter = lane >> 4, q = lane & 15;
    int beg = rp[row], end = rp[row + 1];
    float acc[8];
    #pragma unroll
    for (int k = 0; k < 8; ++k) acc[k] = 0.f;

    int i = beg + quarter;
    for (; i + 4 < end; i += 8) {
        int2 e0 = ent[i], e1 = ent[i + 4];
        uint4 u0 = ((const uint4*)(x + (size_t)e0.x * HD))[q];
        uint4 u1 = ((const uint4*)(x + (size_t)e1.x * HD))[q];
        float v0 = __int_as_float(e0.y), v1 = __int_as_float(e1.y);
        acc[0] += v0 * blo(u0.x) + v1 * blo(u1.x);
        acc[1] += v0 * bhi(u0.x) + v1 * bhi(u1.x);
        acc[2] += v0 * blo(u0.y) + v1 * blo(u1.y);
        acc[3] += v0 * bhi(u0.y) + v1 * bhi(u1.y);
        acc[4] += v0 * blo(u0.z) + v1 * blo(u1.z);
        acc[5] += v0 * bhi(u0.z) + v1 * bhi(u1.z);
        acc[6] += v0 * blo(u0.w) + v1 * blo(u1.w);
        acc[7] += v0 * bhi(u0.w) + v1 * bhi(u1.w);
    }
    for (; i < end; i += 4) {
        int2 e0 = ent[i];
        uint4 u0 = ((const uint4*)(x + (size_t)e0.x * HD))[q];
        float v0 = __int_as_float(e0.y);
        acc[0] += v0 * blo(u0.x);
        acc[1] += v0 * bhi(u0.x);
        acc[2] += v0 * blo(u0.y);
        acc[3] += v0 * bhi(u0.y);
        acc[4] += v0 * blo(u0.z);
        acc[5] += v0 * bhi(u0.z);
        acc[6] += v0 * blo(u0.w);
        acc[7] += v0 * bhi(u0.w);
    }
    // combine the 4 quarters
    #pragma unroll
    for (int k = 0; k < 8; ++k) {
        acc[k] += __shfl_xor(acc[k], 16);
        acc[k] += __shfl_xor(acc[k], 32);
    }
    if (quarter != 0) return;

    if (post == 0) {
        uint4 s;
        s.x = (unsigned)bfr(acc[0]) | ((unsigned)bfr(acc[1]) << 16);
        s.y = (unsigned)bfr(acc[2]) | ((unsigned)bfr(acc[3]) << 16);
        s.z = (unsigned)bfr(acc[4]) | ((unsigned)bfr(acc[5]) << 16);
        s.w = (unsigned)bfr(acc[6]) | ((unsigned)bfr(acc[7]) << 16);
        ((uint4*)(out_bf + (size_t)row * HD))[q] = s;
        return;
    }
    if (post == 1) {
        #pragma unroll
        for (int k = 0; k < 8; ++k) acc[k] = acc[k] >= 0.f ? acc[k] : LEAKY * acc[k];
    }
    float t = 0.f;
    #pragma unroll
    for (int k = 0; k < 8; ++k) t += acc[k];
    #pragma unroll
    for (int off = 1; off < 16; off <<= 1) t += __shfl_xor(t, off);
    float mu = t * (1.f / HD);
    float d[8], vs = 0.f;
    #pragma unroll
    for (int k = 0; k < 8; ++k) { d[k] = acc[k] - mu; vs += d[k] * d[k]; }
    #pragma unroll
    for (int off = 1; off < 16; off <<= 1) vs += __shfl_xor(vs, off);
    float inv = rsqrtf(vs * (1.f / HD) + LN_EPS);

    float4 g0 = ((const float4*)gamma)[2 * q], g1 = ((const float4*)gamma)[2 * q + 1];
    float4 b0 = ((const float4*)beta)[2 * q],  b1 = ((const float4*)beta)[2 * q + 1];
    float4 r0 = ((const float4*)(res + (size_t)row * HD))[2 * q];
    float4 r1 = ((const float4*)(res + (size_t)row * HD))[2 * q + 1];
    float o[8];
    o[0] = d[0] * inv * g0.x + b0.x + r0.x;
    o[1] = d[1] * inv * g0.y + b0.y + r0.y;
    o[2] = d[2] * inv * g0.z + b0.z + r0.z;
    o[3] = d[3] * inv * g0.w + b0.w + r0.w;
    o[4] = d[4] * inv * g1.x + b1.x + r1.x;
    o[5] = d[5] * inv * g1.y + b1.y + r1.y;
    o[6] = d[6] * inv * g1.z + b1.z + r1.z;
    o[7] = d[7] * inv * g1.w + b1.w + r1.w;
    if (post == 1) {
        uint4 s;
        s.x = (unsigned)bfr(o[0]) | ((unsigned)bfr(o[1]) << 16);
        s.y = (unsigned)bfr(o[2]) | ((unsigned)bfr(o[3]) << 16);
        s.z = (unsigned)bfr(o[4]) | ((unsigned)bfr(o[5]) << 16);
        s.w = (unsigned)bfr(o[6]) | ((unsigned)bfr(o[7]) << 16);
        ((uint4*)(out_bf + (size_t)row * HD))[q] = s;
    } else {
        float4 s0 = {o[0], o[1], o[2], o[3]};
        float4 s1 = {o[4], o[5], o[6], o[7]};
        ((float4*)(out_f32 + (size_t)row * HD))[2 * q] = s0;
        ((float4*)(out_f32 + (size_t)row * HD))[2 * q + 1] = s1;
    }
}

extern "C" void kernel_launch(void* const* d_in, const int* in_sizes, int n_in,
                              void* d_out, int out_size, void* d_ws, size_t ws_size,
                              hipStream_t stream) {
    const float* ego   = (const float*)d_in[0];
    const float* vals  = (const float*)d_in[1];
    const float* gamma = (const float*)d_in[2];
    const float* beta  = (const float*)d_in[3];
    const int*   rows  = (const int*)d_in[4];
    const int*   cols  = (const int*)d_in[5];

    const int N   = in_sizes[0] / HD;   // 50000
    const int NNZ = in_sizes[1];        // 800000

    float* out = (float*)d_out;
    char* w = (char*)d_ws;
    unsigned short* ego_bf = (unsigned short*)w; w += (size_t)N * HD * 2;
    unsigned short* bufA   = (unsigned short*)w; w += (size_t)N * HD * 2;
    unsigned short* bufB   = (unsigned short*)w; w += (size_t)N * HD * 2;
    int*  rp_r = (int*)w;  w += (size_t)(N + 4) * 4;
    int*  rp_c = (int*)w;  w += (size_t)(N + 4) * 4;
    int2* ent_r = (int2*)w; w += (size_t)NNZ * 8;
    int2* ent_c = (int2*)w; w += (size_t)NNZ * 8;
    int*  cnt  = (int*)w;  w += (size_t)2 * R * N * 4;
    int*  partials = (int*)w; w += 4096;

    int* cnt_r = cnt;
    int* cnt_c = cnt + (size_t)R * N;

    const int eblocks = (NNZ + 255) / 256;
    const int tiles = (N * R + TILE - 1) / TILE;   // 196 (<=256 for scan_partials)

    // ---- build both CSRs + bf16 ego ----
    hipMemsetAsync(cnt, 0, (size_t)2 * R * N * 4, stream);
    f32_to_bf16<<<(N * HD / 4 + 255) / 256, 256, 0, stream>>>(ego, ego_bf, N * HD / 4);
    histo2<<<eblocks, 256, 0, stream>>>(rows, cols, cnt_r, cnt_c, NNZ, N);
    scan_sum<<<dim3(tiles, 2), 256, 0, stream>>>(cnt, partials, N, tiles);
    scan_partials<<<1, 128, 0, stream>>>(partials, tiles, rp_r, rp_c, N, NNZ);
    scan_apply<<<dim3(tiles, 2), 256, 0, stream>>>(cnt, partials, rp_r, rp_c, N, tiles);
    csr_fill2<<<eblocks, 256, 0, stream>>>(rows, cols, vals, cnt_r, cnt_c,
                                           ent_r, ent_c, NNZ, N);

    const int sblocks = (N + 3) / 4;

    // ---- layer 0 ----
    spmm_bf<<<sblocks, 256, 0, stream>>>(ego_bf, rp_c, ent_c,
                                         nullptr, nullptr, nullptr, bufA, nullptr, N, 0);
    spmm_bf<<<sblocks, 256, 0, stream>>>(bufA, rp_r, ent_r,
                                         ego, gamma, beta, bufB, nullptr, N, 1);
    // ---- layer 1 ----
    spmm_bf<<<sblocks, 256, 0, stream>>>(bufB, rp_c, ent_c,
                                         nullptr, nullptr, nullptr, bufA, nullptr, N, 0);
    spmm_bf<<<sblocks, 256, 0, stream>>>(bufA, rp_r, ent_r,
                                         ego, gamma + HD, beta + HD, nullptr, out, N, 2);
}

// Round 5
// 334.848 us; speedup vs baseline: 16.3237x; 1.2766x over previous
//
#include <hip/hip_runtime.h>
#include <hip/hip_bf16.h>

#define HD 128
#define R 8            // counter replicas
#define RLOG 3
#define LEAKY 0.2f
#define LN_EPS 1e-5f
#define TILE 4096      // scan tile: 256 threads x 16 items

// ---- bf16 helpers (manual, RNE) ----
__device__ __forceinline__ unsigned short bfr(float f) {
    unsigned int b = __float_as_uint(f);
    return (unsigned short)((b + 0x7fffu + ((b >> 16) & 1u)) >> 16);
}
__device__ __forceinline__ float blo(unsigned int u) { return __uint_as_float(u << 16); }
__device__ __forceinline__ float bhi(unsigned int u) { return __uint_as_float(u & 0xffff0000u); }

// ---------- fp32 -> bf16 conversion (ego) ----------
__global__ __launch_bounds__(256) void f32_to_bf16(
    const float* __restrict__ x, unsigned short* __restrict__ y, int n4) {
    int i = blockIdx.x * 256 + threadIdx.x;
    if (i >= n4) return;
    float4 f = ((const float4*)x)[i];
    ushort4 u;
    u.x = bfr(f.x); u.y = bfr(f.y); u.z = bfr(f.z); u.w = bfr(f.w);
    ((ushort4*)y)[i] = u;
}

// ---------- CSR build ----------
// Histogram both key arrays; ALSO record each edge's intra-(bin,replica) rank
// (the atomic's return value) so the fill pass needs no atomics.
__global__ __launch_bounds__(256) void histo2(
    const int* __restrict__ rows, const int* __restrict__ cols,
    int* __restrict__ cnt_r, int* __restrict__ cnt_c,
    int* __restrict__ rank_r, int* __restrict__ rank_c, int nnz, int n) {
    int e = blockIdx.x * 256 + threadIdx.x;
    if (e >= nnz) return;
    int r = blockIdx.x & (R - 1);
    rank_r[e] = atomicAdd(&cnt_r[r * n + rows[e]], 1);
    rank_c[e] = atomicAdd(&cnt_c[r * n + cols[e]], 1);
}

// Exclusive scan over logical order p = bin*R + replica, reading cnt[r*n+b].
__global__ __launch_bounds__(256) void scan_sum(
    const int* __restrict__ cnt, int* __restrict__ partials, int n, int tiles) {
    int a = blockIdx.y;
    const int* base = cnt + (size_t)a * n * R;
    int M = n * R;
    int t0 = blockIdx.x * TILE + threadIdx.x * 16;
    int s = 0;
    #pragma unroll
    for (int j = 0; j < 16; ++j) {
        int p = t0 + j;
        if (p < M) s += base[(p & (R - 1)) * n + (p >> RLOG)];
    }
    #pragma unroll
    for (int off = 32; off; off >>= 1) s += __shfl_xor(s, off);
    __shared__ int ws[4];
    int lane = threadIdx.x & 63, wid = threadIdx.x >> 6;
    if (lane == 0) ws[wid] = s;
    __syncthreads();
    if (threadIdx.x == 0)
        partials[a * tiles + blockIdx.x] = ws[0] + ws[1] + ws[2] + ws[3];
}

// Wave-parallel exclusive scan of tile partials (tiles <= 256), 2 waves.
__global__ __launch_bounds__(128) void scan_partials(
    int* __restrict__ partials, int tiles,
    int* __restrict__ rp_r, int* __restrict__ rp_c, int n, int nnz) {
    int wid = threadIdx.x >> 6, lane = threadIdx.x & 63;
    int* p = partials + wid * tiles;
    int v[4], s = 0;
    #pragma unroll
    for (int j = 0; j < 4; ++j) {
        int idx = lane * 4 + j;
        v[j] = (idx < tiles) ? p[idx] : 0;
        s += v[j];
    }
    int incl = s;
    #pragma unroll
    for (int off = 1; off < 64; off <<= 1) {
        int t = __shfl_up(incl, off);
        if (lane >= off) incl += t;
    }
    int excl = incl - s;
    #pragma unroll
    for (int j = 0; j < 4; ++j) {
        int idx = lane * 4 + j;
        if (idx < tiles) p[idx] = excl;
        excl += v[j];
    }
    if (lane == 0) (wid ? rp_c : rp_r)[n] = nnz;
}

// Re-scan tiles, convert cnt -> exclusive base offsets in-place,
// emit rp[b] (replica-0 offset = bin start).
__global__ __launch_bounds__(256) void scan_apply(
    int* __restrict__ cnt, const int* __restrict__ partials,
    int* __restrict__ rp_r, int* __restrict__ rp_c, int n, int tiles) {
    int a = blockIdx.y;
    int* base = cnt + (size_t)a * n * R;
    int* rp = a ? rp_c : rp_r;
    int M = n * R;
    int t0 = blockIdx.x * TILE + threadIdx.x * 16;
    int v[16];
    int s = 0;
    #pragma unroll
    for (int j = 0; j < 16; ++j) {
        int p = t0 + j;
        v[j] = (p < M) ? base[(p & (R - 1)) * n + (p >> RLOG)] : 0;
        s += v[j];
    }
    int lane = threadIdx.x & 63, wid = threadIdx.x >> 6;
    int incl = s;
    #pragma unroll
    for (int off = 1; off < 64; off <<= 1) {
        int t = __shfl_up(incl, off);
        if (lane >= off) incl += t;
    }
    __shared__ int wsum[4], woff[4];
    if (lane == 63) wsum[wid] = incl;
    __syncthreads();
    if (threadIdx.x == 0) {
        int run = 0;
        #pragma unroll
        for (int w = 0; w < 4; ++w) { woff[w] = run; run += wsum[w]; }
    }
    __syncthreads();
    int excl = partials[a * tiles + blockIdx.x] + woff[wid] + incl - s;
    #pragma unroll
    for (int j = 0; j < 16; ++j) {
        int p = t0 + j;
        if (p < M) {
            int b = p >> RLOG, r = p & (R - 1);
            base[r * n + b] = excl;
            if (r == 0) rp[b] = excl;
            excl += v[j];
        }
    }
}

// Atomic-free fill: p = base[(replica,bin)] + rank[e].
__global__ __launch_bounds__(256) void csr_fill2(
    const int* __restrict__ rows, const int* __restrict__ cols,
    const float* __restrict__ vals,
    const int* __restrict__ base_r, const int* __restrict__ base_c,
    const int* __restrict__ rank_r, const int* __restrict__ rank_c,
    int2* __restrict__ ent_r, int2* __restrict__ ent_c, int nnz, int n) {
    int e = blockIdx.x * 256 + threadIdx.x;
    if (e >= nnz) return;
    int r = blockIdx.x & (R - 1);
    int ro = rows[e], co = cols[e];
    int vb = __float_as_int(vals[e]);
    int p1 = base_r[r * n + ro] + rank_r[e];
    int p2 = base_c[r * n + co] + rank_c[e];
    ent_r[p1] = make_int2(co, vb);
    ent_c[p2] = make_int2(ro, vb);
}

// ---------- bf16-gather SpMM (+ optional fused leaky/LN/residual) ----------
// One wave per output row. Quarter-wave (16 lanes) x 16 B (8 bf16) covers a
// 256 B row; the 4 quarters process interleaved edges, combined at the end.
// post: 0 = none (bf16 out), 1 = leaky+LN+res (bf16 out), 2 = LN+res (fp32 out).
__global__ __launch_bounds__(256) void spmm_bf(
    const unsigned short* __restrict__ x, const int* __restrict__ rp,
    const int2* __restrict__ ent,
    const float* __restrict__ res, const float* __restrict__ gamma,
    const float* __restrict__ beta,
    unsigned short* __restrict__ out_bf, float* __restrict__ out_f32,
    int n, int post) {
    int wid = threadIdx.x >> 6, lane = threadIdx.x & 63;
    int row = blockIdx.x * 4 + wid;
    if (row >= n) return;
    int quarter = lane >> 4, q = lane & 15;
    int beg = rp[row], end = rp[row + 1];
    float acc[8];
    #pragma unroll
    for (int k = 0; k < 8; ++k) acc[k] = 0.f;

    int i = beg + quarter;
    for (; i + 4 < end; i += 8) {
        int2 e0 = ent[i], e1 = ent[i + 4];
        uint4 u0 = ((const uint4*)(x + (size_t)e0.x * HD))[q];
        uint4 u1 = ((const uint4*)(x + (size_t)e1.x * HD))[q];
        float v0 = __int_as_float(e0.y), v1 = __int_as_float(e1.y);
        acc[0] += v0 * blo(u0.x) + v1 * blo(u1.x);
        acc[1] += v0 * bhi(u0.x) + v1 * bhi(u1.x);
        acc[2] += v0 * blo(u0.y) + v1 * blo(u1.y);
        acc[3] += v0 * bhi(u0.y) + v1 * bhi(u1.y);
        acc[4] += v0 * blo(u0.z) + v1 * blo(u1.z);
        acc[5] += v0 * bhi(u0.z) + v1 * bhi(u1.z);
        acc[6] += v0 * blo(u0.w) + v1 * blo(u1.w);
        acc[7] += v0 * bhi(u0.w) + v1 * bhi(u1.w);
    }
    for (; i < end; i += 4) {
        int2 e0 = ent[i];
        uint4 u0 = ((const uint4*)(x + (size_t)e0.x * HD))[q];
        float v0 = __int_as_float(e0.y);
        acc[0] += v0 * blo(u0.x);
        acc[1] += v0 * bhi(u0.x);
        acc[2] += v0 * blo(u0.y);
        acc[3] += v0 * bhi(u0.y);
        acc[4] += v0 * blo(u0.z);
        acc[5] += v0 * bhi(u0.z);
        acc[6] += v0 * blo(u0.w);
        acc[7] += v0 * bhi(u0.w);
    }
    // combine the 4 quarters
    #pragma unroll
    for (int k = 0; k < 8; ++k) {
        acc[k] += __shfl_xor(acc[k], 16);
        acc[k] += __shfl_xor(acc[k], 32);
    }
    if (quarter != 0) return;

    if (post == 0) {
        uint4 s;
        s.x = (unsigned)bfr(acc[0]) | ((unsigned)bfr(acc[1]) << 16);
        s.y = (unsigned)bfr(acc[2]) | ((unsigned)bfr(acc[3]) << 16);
        s.z = (unsigned)bfr(acc[4]) | ((unsigned)bfr(acc[5]) << 16);
        s.w = (unsigned)bfr(acc[6]) | ((unsigned)bfr(acc[7]) << 16);
        ((uint4*)(out_bf + (size_t)row * HD))[q] = s;
        return;
    }
    if (post == 1) {
        #pragma unroll
        for (int k = 0; k < 8; ++k) acc[k] = acc[k] >= 0.f ? acc[k] : LEAKY * acc[k];
    }
    float t = 0.f;
    #pragma unroll
    for (int k = 0; k < 8; ++k) t += acc[k];
    #pragma unroll
    for (int off = 1; off < 16; off <<= 1) t += __shfl_xor(t, off);
    float mu = t * (1.f / HD);
    float d[8], vs = 0.f;
    #pragma unroll
    for (int k = 0; k < 8; ++k) { d[k] = acc[k] - mu; vs += d[k] * d[k]; }
    #pragma unroll
    for (int off = 1; off < 16; off <<= 1) vs += __shfl_xor(vs, off);
    float inv = rsqrtf(vs * (1.f / HD) + LN_EPS);

    float4 g0 = ((const float4*)gamma)[2 * q], g1 = ((const float4*)gamma)[2 * q + 1];
    float4 b0 = ((const float4*)beta)[2 * q],  b1 = ((const float4*)beta)[2 * q + 1];
    float4 r0 = ((const float4*)(res + (size_t)row * HD))[2 * q];
    float4 r1 = ((const float4*)(res + (size_t)row * HD))[2 * q + 1];
    float o[8];
    o[0] = d[0] * inv * g0.x + b0.x + r0.x;
    o[1] = d[1] * inv * g0.y + b0.y + r0.y;
    o[2] = d[2] * inv * g0.z + b0.z + r0.z;
    o[3] = d[3] * inv * g0.w + b0.w + r0.w;
    o[4] = d[4] * inv * g1.x + b1.x + r1.x;
    o[5] = d[5] * inv * g1.y + b1.y + r1.y;
    o[6] = d[6] * inv * g1.z + b1.z + r1.z;
    o[7] = d[7] * inv * g1.w + b1.w + r1.w;
    if (post == 1) {
        uint4 s;
        s.x = (unsigned)bfr(o[0]) | ((unsigned)bfr(o[1]) << 16);
        s.y = (unsigned)bfr(o[2]) | ((unsigned)bfr(o[3]) << 16);
        s.z = (unsigned)bfr(o[4]) | ((unsigned)bfr(o[5]) << 16);
        s.w = (unsigned)bfr(o[6]) | ((unsigned)bfr(o[7]) << 16);
        ((uint4*)(out_bf + (size_t)row * HD))[q] = s;
    } else {
        float4 s0 = {o[0], o[1], o[2], o[3]};
        float4 s1 = {o[4], o[5], o[6], o[7]};
        ((float4*)(out_f32 + (size_t)row * HD))[2 * q] = s0;
        ((float4*)(out_f32 + (size_t)row * HD))[2 * q + 1] = s1;
    }
}

extern "C" void kernel_launch(void* const* d_in, const int* in_sizes, int n_in,
                              void* d_out, int out_size, void* d_ws, size_t ws_size,
                              hipStream_t stream) {
    const float* ego   = (const float*)d_in[0];
    const float* vals  = (const float*)d_in[1];
    const float* gamma = (const float*)d_in[2];
    const float* beta  = (const float*)d_in[3];
    const int*   rows  = (const int*)d_in[4];
    const int*   cols  = (const int*)d_in[5];

    const int N   = in_sizes[0] / HD;   // 50000
    const int NNZ = in_sizes[1];        // 800000

    float* out = (float*)d_out;
    char* w = (char*)d_ws;
    unsigned short* ego_bf = (unsigned short*)w; w += (size_t)N * HD * 2;
    unsigned short* bufA   = (unsigned short*)w; w += (size_t)N * HD * 2;
    unsigned short* bufB   = (unsigned short*)w; w += (size_t)N * HD * 2;
    int*  rp_r = (int*)w;  w += (size_t)(N + 4) * 4;
    int*  rp_c = (int*)w;  w += (size_t)(N + 4) * 4;
    int2* ent_r = (int2*)w; w += (size_t)NNZ * 8;
    int2* ent_c = (int2*)w; w += (size_t)NNZ * 8;
    int*  cnt  = (int*)w;  w += (size_t)2 * R * N * 4;
    int*  rank_r = (int*)w; w += (size_t)NNZ * 4;
    int*  rank_c = (int*)w; w += (size_t)NNZ * 4;
    int*  partials = (int*)w; w += 4096;

    int* cnt_r = cnt;
    int* cnt_c = cnt + (size_t)R * N;

    const int eblocks = (NNZ + 255) / 256;
    const int tiles = (N * R + TILE - 1) / TILE;   // 98 (<=256 for scan_partials)

    // ---- build both CSRs + bf16 ego ----
    hipMemsetAsync(cnt, 0, (size_t)2 * R * N * 4, stream);
    f32_to_bf16<<<(N * HD / 4 + 255) / 256, 256, 0, stream>>>(ego, ego_bf, N * HD / 4);
    histo2<<<eblocks, 256, 0, stream>>>(rows, cols, cnt_r, cnt_c,
                                        rank_r, rank_c, NNZ, N);
    scan_sum<<<dim3(tiles, 2), 256, 0, stream>>>(cnt, partials, N, tiles);
    scan_partials<<<1, 128, 0, stream>>>(partials, tiles, rp_r, rp_c, N, NNZ);
    scan_apply<<<dim3(tiles, 2), 256, 0, stream>>>(cnt, partials, rp_r, rp_c, N, tiles);
    csr_fill2<<<eblocks, 256, 0, stream>>>(rows, cols, vals, cnt_r, cnt_c,
                                           rank_r, rank_c, ent_r, ent_c, NNZ, N);

    const int sblocks = (N + 3) / 4;

    // ---- layer 0 ----
    spmm_bf<<<sblocks, 256, 0, stream>>>(ego_bf, rp_c, ent_c,
                                         nullptr, nullptr, nullptr, bufA, nullptr, N, 0);
    spmm_bf<<<sblocks, 256, 0, stream>>>(bufA, rp_r, ent_r,
                                         ego, gamma, beta, bufB, nullptr, N, 1);
    // ---- layer 1 ----
    spmm_bf<<<sblocks, 256, 0, stream>>>(bufB, rp_c, ent_c,
                                         nullptr, nullptr, nullptr, bufA, nullptr, N, 0);
    spmm_bf<<<sblocks, 256, 0, stream>>>(bufA, rp_r, ent_r,
                                         ego, gamma + HD, beta + HD, nullptr, out, N, 2);
}